// Round 1
// baseline (303.849 us; speedup 1.0000x reference)
//
#include <hip/hip_runtime.h>
#include <cstdint>

// Problem constants
#define BATCH 2
#define TT    4
#define CKD   64      // key channels
#define CVD   256     // value channels
#define NQ    2048    // H*W (queries per batch)
#define MM    8192    // T*H*W (memory positions per batch)
#define TQ    64      // queries per block
#define TM    32      // memory rows per inner iteration
#define MSPLIT 4
#define MCHUNK 2048   // MM/MSPLIT == H*W, so t is constant within a chunk

typedef unsigned short u16;
typedef __bf16 bf16x8 __attribute__((ext_vector_type(8)));
typedef float  f32x4  __attribute__((ext_vector_type(4)));

struct __attribute__((aligned(8))) U16x4 { u16 x, y, z, w; };

__device__ __forceinline__ u16 f2bf(float x) {
    uint32_t u = __float_as_uint(x);
    uint32_t r = (u + 0x7FFFu + ((u >> 16) & 1u)) >> 16;   // RNE
    return (u16)r;
}
__device__ __forceinline__ float bf2f(u16 h) {
    return __uint_as_float(((uint32_t)h) << 16);
}

#define MFMA(a, b, c) __builtin_amdgcn_mfma_f32_16x16x32_bf16((a), (b), (c), 0, 0, 0)

// ---------------------------------------------------------------------------
// Kernel 1: 2x2 average pool of query_value (bilinear 2x downscale, frac=0.5)
// in: [2,256,64,128] -> out channels [0,256) of [2,512,32,64]
// ---------------------------------------------------------------------------
__global__ __launch_bounds__(256) void pool_qv(const float* __restrict__ qv,
                                               float* __restrict__ out) {
    int idx = blockIdx.x * 256 + threadIdx.x;      // [0, 2*256*2048)
    int n  = idx & 2047;
    int bc = idx >> 11;                            // b*256 + c
    int x = n & 63, y = n >> 6;
    const float* ib = qv + (size_t)bc * (64 * 128) + (2 * y) * 128 + 2 * x;
    float2 r0 = *(const float2*)ib;
    float2 r1 = *(const float2*)(ib + 128);
    int b = bc >> 8, c = bc & 255;
    out[((size_t)(b * 512 + c)) * NQ + n] = 0.25f * (r0.x + r0.y + r1.x + r1.y);
}

// ---------------------------------------------------------------------------
// Kernel 2: fused flash attention (no-max softmax: U=sum(exp(S)*V), L=sum(exp(S)))
// Accumulates U into out channels [256,512) via atomicAdd; L into d_ws.
// Grid: 256 blocks = b(2) x ntile(32, TQ=64) x mchunk(4). Block: 256 threads.
// ---------------------------------------------------------------------------
__global__ __launch_bounds__(256, 2)
void flash_attn(const float* __restrict__ keys, const float* __restrict__ vals,
                const float* __restrict__ qkl, float* __restrict__ out,
                float* __restrict__ Lws) {
    // LDS layout (u16 units): Khi[32][72] | Klo[32][72] | Vs[256][40] | Ps[64][40]
    // Q staging (Qhi[64][72], Qlo[64][72]) overlays the Vs/Ps region (pre-loop only).
    __shared__ __align__(16) u16 smem[17408];
    u16* Khi = smem;
    u16* Klo = smem + 2304;
    u16* Vs  = smem + 4608;
    u16* Ps  = smem + 4608 + 10240;
    u16* Qhi = smem + 4608;
    u16* Qlo = smem + 4608 + 4608;

    const int tid    = threadIdx.x;
    const int bx     = blockIdx.x;
    const int mchunk = bx & 3;
    const int ntile  = (bx >> 2) & 31;
    const int b      = bx >> 7;

    const int lane = tid & 63;
    const int w    = tid >> 6;
    const int quad = lane >> 4;
    const int l15  = lane & 15;

    // ---- stage Q tile [64n x 64c] as hi/lo bf16 into LDS (transpose) ----
    {
        const int c  = tid >> 2;        // 0..63
        const int ng = tid & 3;         // n-group of 16
        const float* gq = qkl + ((size_t)(b * CKD + c)) * NQ + ntile * TQ + ng * 16;
        #pragma unroll
        for (int i4 = 0; i4 < 4; ++i4) {
            float4 v = *(const float4*)(gq + i4 * 4);
            float a[4] = {v.x, v.y, v.z, v.w};
            #pragma unroll
            for (int j = 0; j < 4; ++j) {
                int n = ng * 16 + i4 * 4 + j;
                u16 hi = f2bf(a[j]);
                Qhi[n * 72 + c] = hi;
                Qlo[n * 72 + c] = f2bf(a[j] - bf2f(hi));
            }
        }
    }
    __syncthreads();

    // ---- load Q fragments into registers: wave w covers nsubs {2*(w>>1), +1} ----
    bf16x8 qh[2][2], ql[2][2];          // [nsi][kstep]
    {
        const int nsubpair = w >> 1;
        #pragma unroll
        for (int nsi = 0; nsi < 2; ++nsi) {
            int n = (nsubpair * 2 + nsi) * 16 + l15;
            #pragma unroll
            for (int ks = 0; ks < 2; ++ks) {
                qh[nsi][ks] = *(const bf16x8*)&Qhi[n * 72 + ks * 32 + quad * 8];
                ql[nsi][ks] = *(const bf16x8*)&Qlo[n * 72 + ks * 32 + quad * 8];
            }
        }
    }
    __syncthreads();   // Q region about to be overwritten by V staging

    const int t = mchunk;  // chunk == one T slice exactly
    const float* kbase = keys + ((size_t)((b * TT + t) * CKD)) * NQ;
    const float* vbase = vals + ((size_t)((b * TT + t) * CVD)) * NQ;

    f32x4 O[2][8];
    #pragma unroll
    for (int i = 0; i < 2; ++i)
        #pragma unroll
        for (int j = 0; j < 8; ++j)
            O[i][j] = (f32x4){0.f, 0.f, 0.f, 0.f};
    float Lloc[2] = {0.f, 0.f};

    const int msub     = w & 1;         // QK role
    const int nsubpair = w >> 1;        // QK role
    const int npair    = w & 1;         // PV role: n half
    const int chalf    = w >> 1;        // PV role: c half

    for (int it = 0; it < MCHUNK / TM; ++it) {
        const int hw0 = it * TM;
        // ---- stage K (hi/lo) and V (bf16) tiles ----
        {
            const int m4 = (tid & 7) * 4;
            const int c0 = tid >> 3;     // 0..31
            #pragma unroll
            for (int cp = 0; cp < 2; ++cp) {
                int c = c0 + cp * 32;
                float4 v = *(const float4*)(kbase + (size_t)c * NQ + hw0 + m4);
                float a[4] = {v.x, v.y, v.z, v.w};
                #pragma unroll
                for (int i = 0; i < 4; ++i) {
                    u16 hi = f2bf(a[i]);
                    Khi[(m4 + i) * 72 + c] = hi;
                    Klo[(m4 + i) * 72 + c] = f2bf(a[i] - bf2f(hi));
                }
            }
            #pragma unroll
            for (int cp = 0; cp < 8; ++cp) {
                int c = c0 + cp * 32;
                float4 v = *(const float4*)(vbase + (size_t)c * NQ + hw0 + m4);
                U16x4 pk = {f2bf(v.x), f2bf(v.y), f2bf(v.z), f2bf(v.w)};
                *(U16x4*)&Vs[c * 40 + m4] = pk;
            }
        }
        __syncthreads();

        // ---- QK: wave computes S[msub*16..+16][nsubpair*32..+32], 3-term split ----
        f32x4 acc[2];
        acc[0] = (f32x4){0.f, 0.f, 0.f, 0.f};
        acc[1] = (f32x4){0.f, 0.f, 0.f, 0.f};
        #pragma unroll
        for (int ks = 0; ks < 2; ++ks) {
            bf16x8 ah = *(const bf16x8*)&Khi[(msub * 16 + l15) * 72 + ks * 32 + quad * 8];
            bf16x8 al = *(const bf16x8*)&Klo[(msub * 16 + l15) * 72 + ks * 32 + quad * 8];
            #pragma unroll
            for (int nsi = 0; nsi < 2; ++nsi) {
                acc[nsi] = MFMA(ah, qh[nsi][ks], acc[nsi]);
                acc[nsi] = MFMA(ah, ql[nsi][ks], acc[nsi]);
                acc[nsi] = MFMA(al, qh[nsi][ks], acc[nsi]);
            }
        }
        // ---- P = exp(S); write to Ps in A-operand layout [n][m]; accumulate L ----
        #pragma unroll
        for (int nsi = 0; nsi < 2; ++nsi) {
            int n = (nsubpair * 2 + nsi) * 16 + l15;
            float p0 = __expf(acc[nsi][0]);
            float p1 = __expf(acc[nsi][1]);
            float p2 = __expf(acc[nsi][2]);
            float p3 = __expf(acc[nsi][3]);
            Lloc[nsi] += (p0 + p1) + (p2 + p3);
            U16x4 pk = {f2bf(p0), f2bf(p1), f2bf(p2), f2bf(p3)};
            *(U16x4*)&Ps[n * 40 + msub * 16 + quad * 4] = pk;   // rows quad*4+r are contiguous m
        }
        __syncthreads();

        // ---- PV: wave owns O[npair*32..+32][chalf*128..+128] ----
        bf16x8 a2[2];
        #pragma unroll
        for (int nsi2 = 0; nsi2 < 2; ++nsi2)
            a2[nsi2] = *(const bf16x8*)&Ps[(npair * 32 + nsi2 * 16 + l15) * 40 + quad * 8];
        #pragma unroll
        for (int cs = 0; cs < 8; ++cs) {
            bf16x8 bv = *(const bf16x8*)&Vs[(chalf * 128 + cs * 16 + l15) * 40 + quad * 8];
            O[0][cs] = MFMA(a2[0], bv, O[0][cs]);
            O[1][cs] = MFMA(a2[1], bv, O[1][cs]);
        }
        __syncthreads();   // protect K/V/Ps before next staging
    }

    // ---- L: reduce over quads (16 m rows of this wave's msub), atomic to ws ----
    #pragma unroll
    for (int nsi = 0; nsi < 2; ++nsi) {
        float v = Lloc[nsi];
        v += __shfl_xor(v, 16);
        v += __shfl_xor(v, 32);
        if (quad == nsi) {
            int nsub = nsubpair * 2 + nsi;
            atomicAdd(&Lws[b * NQ + ntile * TQ + nsub * 16 + l15], v);
        }
    }

    // ---- U: atomic accumulate into out channels [256,512) ----
    float* obase = out + ((size_t)(b * 512 + 256 + chalf * 128)) * NQ + ntile * TQ + npair * 32;
    #pragma unroll
    for (int nsi2 = 0; nsi2 < 2; ++nsi2) {
        #pragma unroll
        for (int cs = 0; cs < 8; ++cs) {
            int c = cs * 16 + l15;
            #pragma unroll
            for (int r = 0; r < 4; ++r) {
                int n = nsi2 * 16 + quad * 4 + r;
                atomicAdd(obase + (size_t)c * NQ + n, O[nsi2][cs][r]);
            }
        }
    }
}

// ---------------------------------------------------------------------------
// Kernel 3: normalize memory output: out[b,256+c,n] /= L[b,n]
// ---------------------------------------------------------------------------
__global__ __launch_bounds__(256) void div_norm(float* __restrict__ out,
                                                const float* __restrict__ Lws) {
    int idx = blockIdx.x * 256 + threadIdx.x;      // [0, 2*256*2048)
    int n  = idx & 2047;
    int bc = idx >> 11;
    int b = bc >> 8, c = bc & 255;
    size_t o = ((size_t)(b * 512 + 256 + c)) * NQ + n;
    out[o] = out[o] / Lws[b * NQ + n];
}

extern "C" void kernel_launch(void* const* d_in, const int* in_sizes, int n_in,
                              void* d_out, int out_size, void* d_ws, size_t ws_size,
                              hipStream_t stream) {
    const float* qv = (const float*)d_in[0];   // query_value       [2,256,64,128]
    const float* mk = (const float*)d_in[1];   // memory_keys_low   [2,4,64,32,64]
    const float* mv = (const float*)d_in[2];   // memory_values_low [2,4,256,32,64]
    const float* qk = (const float*)d_in[3];   // query_key_low     [2,64,32,64]
    float* out = (float*)d_out;                // [2,512,32,64] fp32
    float* Lws = (float*)d_ws;                 // B*NQ floats (16 KB)

    hipMemsetAsync(d_out, 0, (size_t)out_size * sizeof(float), stream);
    hipMemsetAsync(d_ws, 0, (size_t)BATCH * NQ * sizeof(float), stream);

    pool_qv<<<4096, 256, 0, stream>>>(qv, out);
    flash_attn<<<256, 256, 0, stream>>>(mk, mv, qk, out, Lws);
    div_norm<<<4096, 256, 0, stream>>>(out, Lws);
}

// Round 2
// 239.643 us; speedup vs baseline: 1.2679x; 1.2679x over previous
//
#include <hip/hip_runtime.h>
#include <cstdint>

// Problem constants
#define BATCH 2
#define TT    4
#define CKD   64      // key channels
#define CVD   256     // value channels
#define NQ    2048    // H*W (queries per batch)
#define MM    8192    // T*H*W (memory positions per batch)
#define TQ    64      // queries per block
#define TM    32      // memory rows per inner iteration
#define MSPLIT 8
#define MCHUNK (MM / MSPLIT)   // 1024 = half a T-slice

typedef unsigned short u16;
typedef __bf16 bf16x8 __attribute__((ext_vector_type(8)));
typedef float  f32x4  __attribute__((ext_vector_type(4)));

struct __attribute__((aligned(8)))  U16x4 { u16 x, y, z, w; };
struct __attribute__((aligned(16))) U16x8 { u16 v[8]; };

__device__ __forceinline__ u16 f2bf(float x) {
    uint32_t u = __float_as_uint(x);
    uint32_t r = (u + 0x7FFFu + ((u >> 16) & 1u)) >> 16;   // RNE
    return (u16)r;
}
__device__ __forceinline__ float bf2f(u16 h) {
    return __uint_as_float(((uint32_t)h) << 16);
}

#define MFMA(a, b, c) __builtin_amdgcn_mfma_f32_16x16x32_bf16((a), (b), (c), 0, 0, 0)

// Workspace layout (bytes)
#define WS_VB   0u                         // 8 MB  bf16 V   [bt][c][m]
#define WS_KHI  (8u << 20)                 // 2 MB  bf16 Khi [bt][m][c]  (transposed)
#define WS_KLO  (10u << 20)                // 2 MB  bf16 Klo [bt][m][c]
#define WS_QHI  (12u << 20)                // 512 KB bf16 Qhi [b][n][c]  (transposed)
#define WS_QLO  (WS_QHI + (512u << 10))    // 512 KB
#define WS_L    (WS_QLO + (512u << 10))    // 16 KB fp32 L[b][n]
// total ~13.02 MB

// ---------------------------------------------------------------------------
// prep_v: fp32 V [bt][c][m] -> bf16, same layout. 4.19M elems, 8/thread.
// ---------------------------------------------------------------------------
__global__ __launch_bounds__(256) void prep_v(const float* __restrict__ mv,
                                              u16* __restrict__ vb) {
    int idx = blockIdx.x * 256 + threadIdx.x;          // 0 .. 524287
    const float4* s = (const float4*)mv + (size_t)idx * 2;
    float4 a = s[0], b = s[1];
    U16x8 o;
    o.v[0] = f2bf(a.x); o.v[1] = f2bf(a.y); o.v[2] = f2bf(a.z); o.v[3] = f2bf(a.w);
    o.v[4] = f2bf(b.x); o.v[5] = f2bf(b.y); o.v[6] = f2bf(b.z); o.v[7] = f2bf(b.w);
    *(U16x8*)(vb + (size_t)idx * 8) = o;
}

// ---------------------------------------------------------------------------
// prep_kq: fp32 [g][64][2048] -> bf16 hi/lo transposed [g][2048][64].
// grid = g_count * 64 (32 rows of the transposed output per block).
// ---------------------------------------------------------------------------
__global__ __launch_bounds__(256) void prep_kq(const float* __restrict__ src,
                                               u16* __restrict__ dhi,
                                               u16* __restrict__ dlo) {
    int g  = blockIdx.x >> 6;
    int mg = blockIdx.x & 63;
    int c8 = (threadIdx.x & 7) * 8;
    int m  = mg * 32 + (threadIdx.x >> 3);
    const float* s = src + (size_t)g * 64 * 2048 + m;
    U16x8 hi, lo;
    #pragma unroll
    for (int j = 0; j < 8; ++j) {
        float v = s[(size_t)(c8 + j) * 2048];
        u16 h = f2bf(v);
        hi.v[j] = h;
        lo.v[j] = f2bf(v - bf2f(h));
    }
    size_t o = ((size_t)g * 2048 + m) * 64 + c8;
    *(U16x8*)(dhi + o) = hi;
    *(U16x8*)(dlo + o) = lo;
}

// ---------------------------------------------------------------------------
// pool_qv: 2x2 average pool of query_value -> out channels [0,256)
// ---------------------------------------------------------------------------
__global__ __launch_bounds__(256) void pool_qv(const float* __restrict__ qv,
                                               float* __restrict__ out) {
    int idx = blockIdx.x * 256 + threadIdx.x;
    int n  = idx & 2047;
    int bc = idx >> 11;
    int x = n & 63, y = n >> 6;
    const float* ib = qv + (size_t)bc * (64 * 128) + (2 * y) * 128 + 2 * x;
    float2 r0 = *(const float2*)ib;
    float2 r1 = *(const float2*)(ib + 128);
    int b = bc >> 8, c = bc & 255;
    out[((size_t)(b * 512 + c)) * NQ + n] = 0.25f * (r0.x + r0.y + r1.x + r1.y);
}

// ---------------------------------------------------------------------------
// flash_attn: U=sum(exp(S)*V), L=sum(exp(S)); atomics into out[256,512) + Lws.
// Grid: 512 = b(2) x ntile(32) x mchunk(8). Block 256 = 4 waves.
// All staging is b128 loads of pre-converted bf16 -> ds_write_b128 (padded,
// conflict-free by bank arithmetic). Q fragments load directly from global.
// ---------------------------------------------------------------------------
__global__ __launch_bounds__(256, 2)
void flash_attn(const u16* __restrict__ khi_g, const u16* __restrict__ klo_g,
                const u16* __restrict__ vb_g, const u16* __restrict__ qhi_g,
                const u16* __restrict__ qlo_g, float* __restrict__ out,
                float* __restrict__ Lws) {
    // LDS (u16 units): Khi[32][72] | Klo[32][72] | Vs[256][40] | Ps[64][40]
    __shared__ __align__(16) u16 smem[17408];
    u16* Khi = smem;
    u16* Klo = smem + 2304;
    u16* Vs  = smem + 4608;
    u16* Ps  = smem + 14848;

    const int tid    = threadIdx.x;
    const int bx     = blockIdx.x;
    const int mchunk = bx & 7;
    const int ntile  = (bx >> 3) & 31;
    const int b      = bx >> 8;

    const int lane = tid & 63;
    const int w    = tid >> 6;
    const int quad = lane >> 4;
    const int l15  = lane & 15;

    const int bt      = b * TT + (mchunk >> 1);
    const int hw_base = (mchunk & 1) * MCHUNK;

    // ---- Q fragments straight from pre-transposed global [b][n][c] ----
    bf16x8 qh[2][2], ql[2][2];          // [nsi][kstep]
    {
        const int nbase = ntile * TQ + (w >> 1) * 32;
        #pragma unroll
        for (int nsi = 0; nsi < 2; ++nsi) {
            size_t o = ((size_t)(b * NQ + nbase + nsi * 16 + l15)) * 64 + quad * 8;
            qh[nsi][0] = *(const bf16x8*)&qhi_g[o];
            qh[nsi][1] = *(const bf16x8*)&qhi_g[o + 32];
            ql[nsi][0] = *(const bf16x8*)&qlo_g[o];
            ql[nsi][1] = *(const bf16x8*)&qlo_g[o + 32];
        }
    }

    const u16* kh_base = khi_g + ((size_t)bt * 2048 + hw_base) * 64;
    const u16* kl_base = klo_g + ((size_t)bt * 2048 + hw_base) * 64;
    const u16* v_base  = vb_g + (size_t)bt * CVD * 2048 + hw_base;

    f32x4 O[2][8];
    #pragma unroll
    for (int i = 0; i < 2; ++i)
        #pragma unroll
        for (int j = 0; j < 8; ++j)
            O[i][j] = (f32x4){0.f, 0.f, 0.f, 0.f};
    float Lloc[2] = {0.f, 0.f};

    const int msub     = w & 1;
    const int nsubpair = w >> 1;
    const int npair    = w & 1;
    const int chalf    = w >> 1;

    // staging lane maps
    const int km = tid >> 3;            // 0..31
    const int kc = (tid & 7) * 8;       // 0..56
    const int vc = tid >> 2;            // 0..63
    const int vm = (tid & 3) * 8;       // 0..24

    for (int it = 0; it < MCHUNK / TM; ++it) {
        const int hw0 = it * TM;
        // ---- stage K hi/lo [32m][72c-padded] and V [256c][40m-padded] ----
        *(bf16x8*)&Khi[km * 72 + kc] = *(const bf16x8*)&kh_base[(size_t)(hw0 + km) * 64 + kc];
        *(bf16x8*)&Klo[km * 72 + kc] = *(const bf16x8*)&kl_base[(size_t)(hw0 + km) * 64 + kc];
        #pragma unroll
        for (int p = 0; p < 4; ++p) {
            int c = vc + p * 64;
            *(bf16x8*)&Vs[c * 40 + vm] = *(const bf16x8*)&v_base[(size_t)c * 2048 + hw0 + vm];
        }
        __syncthreads();

        // ---- QK: S[msub*16..+16][nsubpair*32..+32], 3-term hi/lo split ----
        f32x4 acc[2];
        acc[0] = (f32x4){0.f, 0.f, 0.f, 0.f};
        acc[1] = (f32x4){0.f, 0.f, 0.f, 0.f};
        #pragma unroll
        for (int ks = 0; ks < 2; ++ks) {
            bf16x8 ah = *(const bf16x8*)&Khi[(msub * 16 + l15) * 72 + ks * 32 + quad * 8];
            bf16x8 al = *(const bf16x8*)&Klo[(msub * 16 + l15) * 72 + ks * 32 + quad * 8];
            #pragma unroll
            for (int nsi = 0; nsi < 2; ++nsi) {
                acc[nsi] = MFMA(ah, qh[nsi][ks], acc[nsi]);
                acc[nsi] = MFMA(ah, ql[nsi][ks], acc[nsi]);
                acc[nsi] = MFMA(al, qh[nsi][ks], acc[nsi]);
            }
        }
        // ---- P = exp(S) -> Ps[n][m] (A-operand layout); accumulate L ----
        #pragma unroll
        for (int nsi = 0; nsi < 2; ++nsi) {
            int n = (nsubpair * 2 + nsi) * 16 + l15;
            float p0 = __expf(acc[nsi][0]);
            float p1 = __expf(acc[nsi][1]);
            float p2 = __expf(acc[nsi][2]);
            float p3 = __expf(acc[nsi][3]);
            Lloc[nsi] += (p0 + p1) + (p2 + p3);
            U16x4 pk = {f2bf(p0), f2bf(p1), f2bf(p2), f2bf(p3)};
            *(U16x4*)&Ps[n * 40 + msub * 16 + quad * 4] = pk;
        }
        __syncthreads();

        // ---- PV: wave owns O[npair*32..+32][chalf*128..+128] ----
        bf16x8 a2[2];
        #pragma unroll
        for (int nsi2 = 0; nsi2 < 2; ++nsi2)
            a2[nsi2] = *(const bf16x8*)&Ps[(npair * 32 + nsi2 * 16 + l15) * 40 + quad * 8];
        #pragma unroll
        for (int cs = 0; cs < 8; ++cs) {
            bf16x8 bv = *(const bf16x8*)&Vs[(chalf * 128 + cs * 16 + l15) * 40 + quad * 8];
            O[0][cs] = MFMA(a2[0], bv, O[0][cs]);
            O[1][cs] = MFMA(a2[1], bv, O[1][cs]);
        }
        __syncthreads();
    }

    // ---- L reduction: sum over quads, one atomic per (wave, nsi) row set ----
    #pragma unroll
    for (int nsi = 0; nsi < 2; ++nsi) {
        float v = Lloc[nsi];
        v += __shfl_xor(v, 16);
        v += __shfl_xor(v, 32);
        if (quad == nsi) {
            int nsub = nsubpair * 2 + nsi;
            atomicAdd(&Lws[b * NQ + ntile * TQ + nsub * 16 + l15], v);
        }
    }

    // ---- U accumulate into out channels [256,512) ----
    float* obase = out + ((size_t)(b * 512 + 256 + chalf * 128)) * NQ + ntile * TQ + npair * 32;
    #pragma unroll
    for (int nsi2 = 0; nsi2 < 2; ++nsi2) {
        #pragma unroll
        for (int cs = 0; cs < 8; ++cs) {
            int c = cs * 16 + l15;
            #pragma unroll
            for (int r = 0; r < 4; ++r) {
                int n = nsi2 * 16 + quad * 4 + r;
                atomicAdd(obase + (size_t)c * NQ + n, O[nsi2][cs][r]);
            }
        }
    }
}

// ---------------------------------------------------------------------------
// div_norm: out[b,256+c,n] /= L[b,n]
// ---------------------------------------------------------------------------
__global__ __launch_bounds__(256) void div_norm(float* __restrict__ out,
                                                const float* __restrict__ Lws) {
    int idx = blockIdx.x * 256 + threadIdx.x;
    int n  = idx & 2047;
    int bc = idx >> 11;
    int b = bc >> 8, c = bc & 255;
    size_t o = ((size_t)(b * 512 + 256 + c)) * NQ + n;
    out[o] = out[o] / Lws[b * NQ + n];
}

extern "C" void kernel_launch(void* const* d_in, const int* in_sizes, int n_in,
                              void* d_out, int out_size, void* d_ws, size_t ws_size,
                              hipStream_t stream) {
    const float* qv = (const float*)d_in[0];   // query_value       [2,256,64,128]
    const float* mk = (const float*)d_in[1];   // memory_keys_low   [2,4,64,32,64]
    const float* mv = (const float*)d_in[2];   // memory_values_low [2,4,256,32,64]
    const float* qk = (const float*)d_in[3];   // query_key_low     [2,64,32,64]
    float* out = (float*)d_out;                // [2,512,32,64] fp32

    u16*   vb  = (u16*)((char*)d_ws + WS_VB);
    u16*   khi = (u16*)((char*)d_ws + WS_KHI);
    u16*   klo = (u16*)((char*)d_ws + WS_KLO);
    u16*   qhi = (u16*)((char*)d_ws + WS_QHI);
    u16*   qlo = (u16*)((char*)d_ws + WS_QLO);
    float* Lws = (float*)((char*)d_ws + WS_L);

    hipMemsetAsync(d_out, 0, (size_t)out_size * sizeof(float), stream);
    hipMemsetAsync(Lws, 0, (size_t)BATCH * NQ * sizeof(float), stream);

    prep_v<<<2048, 256, 0, stream>>>(mv, vb);
    prep_kq<<<512, 256, 0, stream>>>(mk, khi, klo);    // g = 8 (b*t)
    prep_kq<<<128, 256, 0, stream>>>(qk, qhi, qlo);    // g = 2 (b)
    pool_qv<<<4096, 256, 0, stream>>>(qv, out);
    flash_attn<<<512, 256, 0, stream>>>(khi, klo, vb, qhi, qlo, out, Lws);
    div_norm<<<4096, 256, 0, stream>>>(out, Lws);
}

// Round 3
// 146.096 us; speedup vs baseline: 2.0798x; 1.6403x over previous
//
#include <hip/hip_runtime.h>
#include <cstdint>

// Problem constants
#define BATCH 2
#define TT    4
#define CKD   64      // key channels
#define CVD   256     // value channels
#define NQ    2048    // H*W (queries per batch)
#define MM    8192    // T*H*W (memory positions per batch)
#define TQ    64      // queries per block
#define TM    32      // memory rows per inner iteration
#define MSPLIT 8
#define MCHUNK (MM / MSPLIT)   // 1024 = half a T-slice
#define NIT    (MCHUNK / TM)   // 32

typedef unsigned short u16;
typedef __bf16 bf16x8 __attribute__((ext_vector_type(8)));
typedef float  f32x4  __attribute__((ext_vector_type(4)));

struct __attribute__((aligned(8)))  U16x4 { u16 x, y, z, w; };
struct __attribute__((aligned(16))) U16x8 { u16 v[8]; };

__device__ __forceinline__ u16 f2bf(float x) {
    uint32_t u = __float_as_uint(x);
    uint32_t r = (u + 0x7FFFu + ((u >> 16) & 1u)) >> 16;   // RNE
    return (u16)r;
}
__device__ __forceinline__ float bf2f(u16 h) {
    return __uint_as_float(((uint32_t)h) << 16);
}

#define MFMA(a, b, c) __builtin_amdgcn_mfma_f32_16x16x32_bf16((a), (b), (c), 0, 0, 0)

// Workspace layout (bytes)
#define WS_VB   0u                          // 8 MB   bf16 V   [bt][c][m]
#define WS_KHI  8388608u                    // 2 MB   bf16 Khi [bt][m][c]
#define WS_KLO  10485760u                   // 2 MB   bf16 Klo [bt][m][c]
#define WS_QHI  12582912u                   // 512 KB bf16 Qhi [b][n][c]
#define WS_QLO  13107200u                   // 512 KB
#define WS_LP   13631488u                   // 128 KB fp32 Lp[ms][b][n]  (atomic, tiny)
#define WS_UP   13762560u                   // 32 MB  fp32 Up[ms][b][n][c] (plain stores)
// total ~47.3 MB

// ---------------------------------------------------------------------------
// prep_v: fp32 V [bt][c][m] -> bf16, same layout. 4.19M elems, 8/thread.
// ---------------------------------------------------------------------------
__global__ __launch_bounds__(256) void prep_v(const float* __restrict__ mv,
                                              u16* __restrict__ vb) {
    int idx = blockIdx.x * 256 + threadIdx.x;          // 0 .. 524287
    const float4* s = (const float4*)mv + (size_t)idx * 2;
    float4 a = s[0], b = s[1];
    U16x8 o;
    o.v[0] = f2bf(a.x); o.v[1] = f2bf(a.y); o.v[2] = f2bf(a.z); o.v[3] = f2bf(a.w);
    o.v[4] = f2bf(b.x); o.v[5] = f2bf(b.y); o.v[6] = f2bf(b.z); o.v[7] = f2bf(b.w);
    *(U16x8*)(vb + (size_t)idx * 8) = o;
}

// ---------------------------------------------------------------------------
// prep_kq: fp32 [g][64][2048] -> bf16 hi/lo transposed [g][2048][64].
// ---------------------------------------------------------------------------
__global__ __launch_bounds__(256) void prep_kq(const float* __restrict__ src,
                                               u16* __restrict__ dhi,
                                               u16* __restrict__ dlo) {
    int g  = blockIdx.x >> 6;
    int mg = blockIdx.x & 63;
    int c8 = (threadIdx.x & 7) * 8;
    int m  = mg * 32 + (threadIdx.x >> 3);
    const float* s = src + (size_t)g * 64 * 2048 + m;
    U16x8 hi, lo;
    #pragma unroll
    for (int j = 0; j < 8; ++j) {
        float v = s[(size_t)(c8 + j) * 2048];
        u16 h = f2bf(v);
        hi.v[j] = h;
        lo.v[j] = f2bf(v - bf2f(h));
    }
    size_t o = ((size_t)g * 2048 + m) * 64 + c8;
    *(U16x8*)(dhi + o) = hi;
    *(U16x8*)(dlo + o) = lo;
}

// ---------------------------------------------------------------------------
// pool_qv: 2x2 average pool of query_value -> out channels [0,256)
// ---------------------------------------------------------------------------
__global__ __launch_bounds__(256) void pool_qv(const float* __restrict__ qv,
                                               float* __restrict__ out) {
    int idx = blockIdx.x * 256 + threadIdx.x;
    int n  = idx & 2047;
    int bc = idx >> 11;
    int x = n & 63, y = n >> 6;
    const float* ib = qv + (size_t)bc * (64 * 128) + (2 * y) * 128 + 2 * x;
    float2 r0 = *(const float2*)ib;
    float2 r1 = *(const float2*)(ib + 128);
    int b = bc >> 8, c = bc & 255;
    out[((size_t)(b * 512 + c)) * NQ + n] = 0.25f * (r0.x + r0.y + r1.x + r1.y);
}

// ---------------------------------------------------------------------------
// flash_attn: U=sum(exp(S)*V) partials -> Up (plain coalesced stores, [n][c]),
// L partials -> Lp (tiny atomic path). One-iteration register prefetch of the
// K/V staging loads hides global latency behind the MFMA/barrier spans.
// Grid: 512 = b(2) x ntile(32) x mchunk(8). Block 256 = 4 waves.
// ---------------------------------------------------------------------------
__global__ __launch_bounds__(256, 2)
void flash_attn(const u16* __restrict__ khi_g, const u16* __restrict__ klo_g,
                const u16* __restrict__ vb_g, const u16* __restrict__ qhi_g,
                const u16* __restrict__ qlo_g, float* __restrict__ Up,
                float* __restrict__ Lp) {
    // LDS (u16 units): Khi[32][72] | Klo[32][72] | Vs[256][40] | Ps[64][40]
    __shared__ __align__(16) u16 smem[17408];
    u16* Khi = smem;
    u16* Klo = smem + 2304;
    u16* Vs  = smem + 4608;
    u16* Ps  = smem + 14848;

    const int tid    = threadIdx.x;
    const int bx     = blockIdx.x;
    const int mchunk = bx & 7;
    const int ntile  = (bx >> 3) & 31;
    const int b      = bx >> 8;

    const int lane = tid & 63;
    const int w    = tid >> 6;
    const int quad = lane >> 4;
    const int l15  = lane & 15;

    const int bt      = b * TT + (mchunk >> 1);
    const int hw_base = (mchunk & 1) * MCHUNK;

    // ---- Q fragments straight from pre-transposed global [b][n][c] ----
    bf16x8 qh[2][2], ql[2][2];          // [nsi][kstep]
    {
        const int nbase = ntile * TQ + (w >> 1) * 32;
        #pragma unroll
        for (int nsi = 0; nsi < 2; ++nsi) {
            size_t o = ((size_t)(b * NQ + nbase + nsi * 16 + l15)) * 64 + quad * 8;
            qh[nsi][0] = *(const bf16x8*)&qhi_g[o];
            qh[nsi][1] = *(const bf16x8*)&qhi_g[o + 32];
            ql[nsi][0] = *(const bf16x8*)&qlo_g[o];
            ql[nsi][1] = *(const bf16x8*)&qlo_g[o + 32];
        }
    }

    const u16* kh_base = khi_g + ((size_t)bt * 2048 + hw_base) * 64;
    const u16* kl_base = klo_g + ((size_t)bt * 2048 + hw_base) * 64;
    const u16* v_base  = vb_g + (size_t)bt * CVD * 2048 + hw_base;

    f32x4 O[2][8];
    #pragma unroll
    for (int i = 0; i < 2; ++i)
        #pragma unroll
        for (int j = 0; j < 8; ++j)
            O[i][j] = (f32x4){0.f, 0.f, 0.f, 0.f};
    float Lloc[2] = {0.f, 0.f};

    const int msub     = w & 1;
    const int nsubpair = w >> 1;
    const int npair    = w & 1;
    const int chalf    = w >> 1;

    // staging lane maps
    const int km = tid >> 3;            // 0..31
    const int kc = (tid & 7) * 8;       // 0..56
    const int vc = tid >> 2;            // 0..63
    const int vm = (tid & 3) * 8;       // 0..24

    // ---- prologue: prefetch iter 0 into registers ----
    bf16x8 kh_r = *(const bf16x8*)&kh_base[(size_t)km * 64 + kc];
    bf16x8 kl_r = *(const bf16x8*)&kl_base[(size_t)km * 64 + kc];
    bf16x8 v_r[4];
    #pragma unroll
    for (int p = 0; p < 4; ++p)
        v_r[p] = *(const bf16x8*)&v_base[(size_t)(vc + p * 64) * 2048 + vm];

    for (int it = 0; it < NIT; ++it) {
        // ---- stage prefetched tile into LDS ----
        *(bf16x8*)&Khi[km * 72 + kc] = kh_r;
        *(bf16x8*)&Klo[km * 72 + kc] = kl_r;
        #pragma unroll
        for (int p = 0; p < 4; ++p)
            *(bf16x8*)&Vs[(vc + p * 64) * 40 + vm] = v_r[p];
        __syncthreads();

        // ---- issue next iteration's loads (consumed after 2 barriers) ----
        if (it + 1 < NIT) {
            const int hw1 = (it + 1) * TM;
            kh_r = *(const bf16x8*)&kh_base[(size_t)(hw1 + km) * 64 + kc];
            kl_r = *(const bf16x8*)&kl_base[(size_t)(hw1 + km) * 64 + kc];
            #pragma unroll
            for (int p = 0; p < 4; ++p)
                v_r[p] = *(const bf16x8*)&v_base[(size_t)(vc + p * 64) * 2048 + hw1 + vm];
        }

        // ---- QK: S[msub*16..+16][nsubpair*32..+32], 3-term hi/lo split ----
        f32x4 acc[2];
        acc[0] = (f32x4){0.f, 0.f, 0.f, 0.f};
        acc[1] = (f32x4){0.f, 0.f, 0.f, 0.f};
        #pragma unroll
        for (int ks = 0; ks < 2; ++ks) {
            bf16x8 ah = *(const bf16x8*)&Khi[(msub * 16 + l15) * 72 + ks * 32 + quad * 8];
            bf16x8 al = *(const bf16x8*)&Klo[(msub * 16 + l15) * 72 + ks * 32 + quad * 8];
            #pragma unroll
            for (int nsi = 0; nsi < 2; ++nsi) {
                acc[nsi] = MFMA(ah, qh[nsi][ks], acc[nsi]);
                acc[nsi] = MFMA(ah, ql[nsi][ks], acc[nsi]);
                acc[nsi] = MFMA(al, qh[nsi][ks], acc[nsi]);
            }
        }
        // ---- P = exp(S) -> Ps[n][m] (A-operand layout); accumulate L ----
        #pragma unroll
        for (int nsi = 0; nsi < 2; ++nsi) {
            int n = (nsubpair * 2 + nsi) * 16 + l15;
            float p0 = __expf(acc[nsi][0]);
            float p1 = __expf(acc[nsi][1]);
            float p2 = __expf(acc[nsi][2]);
            float p3 = __expf(acc[nsi][3]);
            Lloc[nsi] += (p0 + p1) + (p2 + p3);
            U16x4 pk = {f2bf(p0), f2bf(p1), f2bf(p2), f2bf(p3)};
            *(U16x4*)&Ps[n * 40 + msub * 16 + quad * 4] = pk;
        }
        __syncthreads();

        // ---- PV: wave owns O[npair*32..+32][chalf*128..+128] ----
        bf16x8 a2[2];
        #pragma unroll
        for (int nsi2 = 0; nsi2 < 2; ++nsi2)
            a2[nsi2] = *(const bf16x8*)&Ps[(npair * 32 + nsi2 * 16 + l15) * 40 + quad * 8];
        #pragma unroll
        for (int cs = 0; cs < 8; ++cs) {
            bf16x8 bv = *(const bf16x8*)&Vs[(chalf * 128 + cs * 16 + l15) * 40 + quad * 8];
            O[0][cs] = MFMA(a2[0], bv, O[0][cs]);
            O[1][cs] = MFMA(a2[1], bv, O[1][cs]);
        }
        __syncthreads();
    }

    // ---- L partials: fold quads via shuffle, tiny atomic into Lp ----
    #pragma unroll
    for (int nsi = 0; nsi < 2; ++nsi) {
        float v = Lloc[nsi];
        v += __shfl_xor(v, 16);
        v += __shfl_xor(v, 32);
        if (quad == nsi) {
            int nsub = nsubpair * 2 + nsi;
            atomicAdd(&Lp[((size_t)mchunk * BATCH + b) * NQ + ntile * TQ + nsub * 16 + l15], v);
        }
    }

    // ---- U partials: plain coalesced stores, layout [ms][b][n][c] ----
    // lane-consecutive l15 -> consecutive c: 64B sectors per quad-group.
    float* ubase = Up + (((size_t)mchunk * BATCH + b) * NQ + ntile * TQ) * CVD
                 + (size_t)(npair * 32) * CVD + chalf * 128;
    #pragma unroll
    for (int nsi2 = 0; nsi2 < 2; ++nsi2) {
        #pragma unroll
        for (int cs = 0; cs < 8; ++cs) {
            #pragma unroll
            for (int r = 0; r < 4; ++r) {
                int n_local = nsi2 * 16 + quad * 4 + r;
                ubase[(size_t)n_local * CVD + cs * 16 + l15] = O[nsi2][cs][r];
            }
        }
    }
}

// ---------------------------------------------------------------------------
// reduce_div: out[b,256+c,n] = (sum_ms Up[ms][b][n][c]) / (sum_ms Lp[ms][b][n])
// Block = (b, 16-n slab): reads 8 contiguous 16KB slabs, accumulates,
// divides, transposes [n][c]->[c][n] via padded LDS, writes out.
// Grid: 256 = b(2) x nslab(128). Block 256.
// ---------------------------------------------------------------------------
__global__ __launch_bounds__(256) void reduce_div(const float* __restrict__ Up,
                                                  const float* __restrict__ Lp,
                                                  float* __restrict__ out) {
    __shared__ float lds[16 * 257];
    const int tid = threadIdx.x;
    const int b   = blockIdx.x >> 7;
    const int n0  = (blockIdx.x & 127) * 16;

    float acc[16];
    #pragma unroll
    for (int j = 0; j < 16; ++j) acc[j] = 0.f;

    for (int ms = 0; ms < MSPLIT; ++ms) {
        const float* sb = Up + (((size_t)ms * BATCH + b) * NQ + n0) * CVD + tid * 16;
        #pragma unroll
        for (int k = 0; k < 4; ++k) {
            float4 v = *(const float4*)(sb + k * 4);
            acc[k * 4 + 0] += v.x; acc[k * 4 + 1] += v.y;
            acc[k * 4 + 2] += v.z; acc[k * 4 + 3] += v.w;
        }
    }

    const int n_local = tid >> 4;
    const int c0      = (tid & 15) * 16;
    float Lsum = 0.f;
    for (int ms = 0; ms < MSPLIT; ++ms)
        Lsum += Lp[((size_t)ms * BATCH + b) * NQ + n0 + n_local];
    const float inv = 1.0f / Lsum;

    #pragma unroll
    for (int j = 0; j < 16; ++j)
        lds[n_local * 257 + c0 + j] = acc[j] * inv;
    __syncthreads();

    // write out[b][256+c][n0..n0+16): c = tid
    float* ob = out + ((size_t)(b * 512 + 256 + tid)) * NQ + n0;
    #pragma unroll
    for (int k = 0; k < 4; ++k) {
        float4 v;
        v.x = lds[(4 * k + 0) * 257 + tid];
        v.y = lds[(4 * k + 1) * 257 + tid];
        v.z = lds[(4 * k + 2) * 257 + tid];
        v.w = lds[(4 * k + 3) * 257 + tid];
        *(float4*)(ob + 4 * k) = v;
    }
}

extern "C" void kernel_launch(void* const* d_in, const int* in_sizes, int n_in,
                              void* d_out, int out_size, void* d_ws, size_t ws_size,
                              hipStream_t stream) {
    const float* qv = (const float*)d_in[0];   // query_value       [2,256,64,128]
    const float* mk = (const float*)d_in[1];   // memory_keys_low   [2,4,64,32,64]
    const float* mv = (const float*)d_in[2];   // memory_values_low [2,4,256,32,64]
    const float* qk = (const float*)d_in[3];   // query_key_low     [2,64,32,64]
    float* out = (float*)d_out;                // [2,512,32,64] fp32

    u16*   vb  = (u16*)((char*)d_ws + WS_VB);
    u16*   khi = (u16*)((char*)d_ws + WS_KHI);
    u16*   klo = (u16*)((char*)d_ws + WS_KLO);
    u16*   qhi = (u16*)((char*)d_ws + WS_QHI);
    u16*   qlo = (u16*)((char*)d_ws + WS_QLO);
    float* Lp  = (float*)((char*)d_ws + WS_LP);
    float* Up  = (float*)((char*)d_ws + WS_UP);

    hipMemsetAsync(Lp, 0, (size_t)MSPLIT * BATCH * NQ * sizeof(float), stream);

    prep_v<<<2048, 256, 0, stream>>>(mv, vb);
    prep_kq<<<512, 256, 0, stream>>>(mk, khi, klo);    // g = 8 (b*t)
    prep_kq<<<128, 256, 0, stream>>>(qk, qhi, qlo);    // g = 2 (b)
    pool_qv<<<4096, 256, 0, stream>>>(qv, out);
    flash_attn<<<512, 256, 0, stream>>>(khi, klo, vb, qhi, qlo, Up, Lp);
    reduce_div<<<256, 256, 0, stream>>>(Up, Lp, out);
}

// Round 4
// 138.089 us; speedup vs baseline: 2.2004x; 1.0580x over previous
//
#include <hip/hip_runtime.h>
#include <cstdint>

// Problem constants
#define BATCH 2
#define TT    4
#define CKD   64      // key channels
#define CVD   256     // value channels
#define NQ    2048    // H*W (queries per batch)
#define MM    8192    // T*H*W (memory positions per batch)
#define TQ    64      // queries per block
#define TM    32      // memory rows per inner iteration
#define MSPLIT 8
#define MCHUNK (MM / MSPLIT)   // 1024 = half a T-slice
#define NIT    (MCHUNK / TM)   // 32

typedef unsigned short u16;
typedef __bf16 bf16x8 __attribute__((ext_vector_type(8)));
typedef float  f32x4  __attribute__((ext_vector_type(4)));

struct __attribute__((aligned(8)))  U16x4 { u16 x, y, z, w; };
struct __attribute__((aligned(16))) U16x8 { u16 v[8]; };

__device__ __forceinline__ u16 f2bf(float x) {
    uint32_t u = __float_as_uint(x);
    uint32_t r = (u + 0x7FFFu + ((u >> 16) & 1u)) >> 16;   // RNE
    return (u16)r;
}
__device__ __forceinline__ float bf2f(u16 h) {
    return __uint_as_float(((uint32_t)h) << 16);
}

#define MFMA(a, b, c) __builtin_amdgcn_mfma_f32_16x16x32_bf16((a), (b), (c), 0, 0, 0)

// Workspace layout (bytes)
#define WS_VB   0u                          // 8 MB   bf16 V   [bt][c][m]
#define WS_KHI  8388608u                    // 2 MB   bf16 Khi [bt][m][c]
#define WS_KLO  10485760u                   // 2 MB   bf16 Klo [bt][m][c]
#define WS_QHI  12582912u                   // 512 KB bf16 Qhi [b][n][c]
#define WS_QLO  13107200u                   // 512 KB
#define WS_LP   13631488u                   // 256 KB fp32 Lp[ms][msub][b][n] (plain stores)
#define WS_UP   13893632u                   // 32 MB  fp32 Up[ms][b][n][c]   (plain stores)
// total ~47.4 MB

// ---------------------------------------------------------------------------
// prep_fused: one launch replacing pool_qv / prep_v / prep_kq(mk) / prep_kq(qk).
// Block-range switch (block-uniform branch, no divergence):
//   [0,4096)    pool_qv: 2x2 avg-pool query_value -> out channels [0,256)
//   [4096,6144) prep_v : fp32 V -> bf16, same [bt][c][m] layout
//   [6144,6656) prep_kq(mk): fp32 [g][64][2048] -> bf16 hi/lo transposed
//   [6656,6784) prep_kq(qk): same for query_key_low
// ---------------------------------------------------------------------------
__global__ __launch_bounds__(256)
void prep_fused(const float* __restrict__ qv, const float* __restrict__ mk,
                const float* __restrict__ qk, const float* __restrict__ mv,
                float* __restrict__ out, u16* __restrict__ vb,
                u16* __restrict__ khi, u16* __restrict__ klo,
                u16* __restrict__ qhi, u16* __restrict__ qlo) {
    const int bid = blockIdx.x;
    const int tid = threadIdx.x;

    if (bid < 4096) {
        // ---- pool_qv ----
        int idx = bid * 256 + tid;
        int n  = idx & 2047;
        int bc = idx >> 11;
        int x = n & 63, y = n >> 6;
        const float* ib = qv + (size_t)bc * (64 * 128) + (2 * y) * 128 + 2 * x;
        float2 r0 = *(const float2*)ib;
        float2 r1 = *(const float2*)(ib + 128);
        int b = bc >> 8, c = bc & 255;
        out[((size_t)(b * 512 + c)) * NQ + n] = 0.25f * (r0.x + r0.y + r1.x + r1.y);
    } else if (bid < 6144) {
        // ---- prep_v ----
        int idx = (bid - 4096) * 256 + tid;        // 0 .. 524287
        const float4* s = (const float4*)mv + (size_t)idx * 2;
        float4 a = s[0], b = s[1];
        U16x8 o;
        o.v[0] = f2bf(a.x); o.v[1] = f2bf(a.y); o.v[2] = f2bf(a.z); o.v[3] = f2bf(a.w);
        o.v[4] = f2bf(b.x); o.v[5] = f2bf(b.y); o.v[6] = f2bf(b.z); o.v[7] = f2bf(b.w);
        *(U16x8*)(vb + (size_t)idx * 8) = o;
    } else {
        // ---- prep_kq (mk: 512 blocks, qk: 128 blocks) ----
        const float* src;
        u16 *dhi, *dlo;
        int blk;
        if (bid < 6656) { src = mk; dhi = khi; dlo = klo; blk = bid - 6144; }
        else            { src = qk; dhi = qhi; dlo = qlo; blk = bid - 6656; }
        int g  = blk >> 6;
        int mg = blk & 63;
        int c8 = (tid & 7) * 8;
        int m  = mg * 32 + (tid >> 3);
        const float* s = src + (size_t)g * 64 * 2048 + m;
        U16x8 hi, lo;
        #pragma unroll
        for (int j = 0; j < 8; ++j) {
            float v = s[(size_t)(c8 + j) * 2048];
            u16 h = f2bf(v);
            hi.v[j] = h;
            lo.v[j] = f2bf(v - bf2f(h));
        }
        size_t o = ((size_t)g * 2048 + m) * 64 + c8;
        *(U16x8*)(dhi + o) = hi;
        *(U16x8*)(dlo + o) = lo;
    }
}

// ---------------------------------------------------------------------------
// flash_attn: U=sum(exp(S)*V) partials -> Up (plain stores, [n][c]),
// L partials -> Lp[ms][msub][b][n] (plain stores, no atomics, no memset).
// Double-buffered LDS (K/V/Ps x2): 2 barriers per iteration.
//   write buf p | sync | QK(reads buf p) -> Ps(buf p) | sync | PV(reads buf p)
// Next iter's staging (buf p^1) needs no barrier vs PV(buf p); buf-p rewrite
// at it+2 is separated from PV(it) reads by two barriers (lgkmcnt(0) drain
// before s_barrier guarantees read completion).
// Grid: 512 = b(2) x ntile(32) x mchunk(8). Block 256 = 4 waves.
// ---------------------------------------------------------------------------
__global__ __launch_bounds__(256, 2)
void flash_attn(const u16* __restrict__ khi_g, const u16* __restrict__ klo_g,
                const u16* __restrict__ vb_g, const u16* __restrict__ qhi_g,
                const u16* __restrict__ qlo_g, float* __restrict__ Up,
                float* __restrict__ Lp) {
    // Per buffer (u16 units): Khi[32][72] | Klo[32][72] | Vs[256][40] | Ps[64][40]
    __shared__ __align__(16) u16 smem[2][17408];

    const int tid    = threadIdx.x;
    const int bx     = blockIdx.x;
    const int mchunk = bx & 7;
    const int ntile  = (bx >> 3) & 31;
    const int b      = bx >> 8;

    const int lane = tid & 63;
    const int w    = tid >> 6;
    const int quad = lane >> 4;
    const int l15  = lane & 15;

    const int bt      = b * TT + (mchunk >> 1);
    const int hw_base = (mchunk & 1) * MCHUNK;

    // ---- Q fragments straight from pre-transposed global [b][n][c] ----
    bf16x8 qh[2][2], ql[2][2];          // [nsi][kstep]
    {
        const int nbase = ntile * TQ + (w >> 1) * 32;
        #pragma unroll
        for (int nsi = 0; nsi < 2; ++nsi) {
            size_t o = ((size_t)(b * NQ + nbase + nsi * 16 + l15)) * 64 + quad * 8;
            qh[nsi][0] = *(const bf16x8*)&qhi_g[o];
            qh[nsi][1] = *(const bf16x8*)&qhi_g[o + 32];
            ql[nsi][0] = *(const bf16x8*)&qlo_g[o];
            ql[nsi][1] = *(const bf16x8*)&qlo_g[o + 32];
        }
    }

    const u16* kh_base = khi_g + ((size_t)bt * 2048 + hw_base) * 64;
    const u16* kl_base = klo_g + ((size_t)bt * 2048 + hw_base) * 64;
    const u16* v_base  = vb_g + (size_t)bt * CVD * 2048 + hw_base;

    f32x4 O[2][8];
    #pragma unroll
    for (int i = 0; i < 2; ++i)
        #pragma unroll
        for (int j = 0; j < 8; ++j)
            O[i][j] = (f32x4){0.f, 0.f, 0.f, 0.f};
    float Lloc[2] = {0.f, 0.f};

    const int msub     = w & 1;
    const int nsubpair = w >> 1;
    const int npair    = w & 1;
    const int chalf    = w >> 1;

    // staging lane maps
    const int km = tid >> 3;            // 0..31
    const int kc = (tid & 7) * 8;       // 0..56
    const int vc = tid >> 2;            // 0..63
    const int vm = (tid & 3) * 8;       // 0..24

    // ---- prologue: prefetch iter 0 into registers ----
    bf16x8 kh_r = *(const bf16x8*)&kh_base[(size_t)km * 64 + kc];
    bf16x8 kl_r = *(const bf16x8*)&kl_base[(size_t)km * 64 + kc];
    bf16x8 v_r[4];
    #pragma unroll
    for (int p = 0; p < 4; ++p)
        v_r[p] = *(const bf16x8*)&v_base[(size_t)(vc + p * 64) * 2048 + vm];

    #pragma unroll 2
    for (int it = 0; it < NIT; ++it) {
        u16* Khi = smem[it & 1];
        u16* Klo = Khi + 2304;
        u16* Vs  = Khi + 4608;
        u16* Ps  = Khi + 14848;

        // ---- stage prefetched tile into this iteration's buffer ----
        *(bf16x8*)&Khi[km * 72 + kc] = kh_r;
        *(bf16x8*)&Klo[km * 72 + kc] = kl_r;
        #pragma unroll
        for (int p = 0; p < 4; ++p)
            *(bf16x8*)&Vs[(vc + p * 64) * 40 + vm] = v_r[p];

        // ---- issue next iteration's global loads (registers now dead) ----
        if (it + 1 < NIT) {
            const int hw1 = (it + 1) * TM;
            kh_r = *(const bf16x8*)&kh_base[(size_t)(hw1 + km) * 64 + kc];
            kl_r = *(const bf16x8*)&kl_base[(size_t)(hw1 + km) * 64 + kc];
            #pragma unroll
            for (int p = 0; p < 4; ++p)
                v_r[p] = *(const bf16x8*)&v_base[(size_t)(vc + p * 64) * 2048 + hw1 + vm];
        }
        __syncthreads();

        // ---- QK: S[msub*16..+16][nsubpair*32..+32], 3-term hi/lo split ----
        f32x4 acc[2];
        acc[0] = (f32x4){0.f, 0.f, 0.f, 0.f};
        acc[1] = (f32x4){0.f, 0.f, 0.f, 0.f};
        #pragma unroll
        for (int ks = 0; ks < 2; ++ks) {
            bf16x8 ah = *(const bf16x8*)&Khi[(msub * 16 + l15) * 72 + ks * 32 + quad * 8];
            bf16x8 al = *(const bf16x8*)&Klo[(msub * 16 + l15) * 72 + ks * 32 + quad * 8];
            #pragma unroll
            for (int nsi = 0; nsi < 2; ++nsi) {
                acc[nsi] = MFMA(ah, qh[nsi][ks], acc[nsi]);
                acc[nsi] = MFMA(ah, ql[nsi][ks], acc[nsi]);
                acc[nsi] = MFMA(al, qh[nsi][ks], acc[nsi]);
            }
        }
        // ---- P = exp(S) -> Ps[n][m] (A-operand layout); accumulate L ----
        #pragma unroll
        for (int nsi = 0; nsi < 2; ++nsi) {
            int n = (nsubpair * 2 + nsi) * 16 + l15;
            float p0 = __expf(acc[nsi][0]);
            float p1 = __expf(acc[nsi][1]);
            float p2 = __expf(acc[nsi][2]);
            float p3 = __expf(acc[nsi][3]);
            Lloc[nsi] += (p0 + p1) + (p2 + p3);
            U16x4 pk = {f2bf(p0), f2bf(p1), f2bf(p2), f2bf(p3)};
            *(U16x4*)&Ps[n * 40 + msub * 16 + quad * 4] = pk;
        }
        __syncthreads();

        // ---- PV: wave owns O[npair*32..+32][chalf*128..+128] ----
        bf16x8 a2[2];
        #pragma unroll
        for (int nsi2 = 0; nsi2 < 2; ++nsi2)
            a2[nsi2] = *(const bf16x8*)&Ps[(npair * 32 + nsi2 * 16 + l15) * 40 + quad * 8];
        #pragma unroll
        for (int cs = 0; cs < 8; ++cs) {
            bf16x8 bv = *(const bf16x8*)&Vs[(chalf * 128 + cs * 16 + l15) * 40 + quad * 8];
            O[0][cs] = MFMA(a2[0], bv, O[0][cs]);
            O[1][cs] = MFMA(a2[1], bv, O[1][cs]);
        }
        // no barrier: next staging writes the other buffer
    }

    // ---- L partials: fold quads via shuffle, plain store (disjoint slices) ----
    #pragma unroll
    for (int nsi = 0; nsi < 2; ++nsi) {
        float v = Lloc[nsi];
        v += __shfl_xor(v, 16);
        v += __shfl_xor(v, 32);
        if (quad == nsi) {
            int nsub = nsubpair * 2 + nsi;
            Lp[(((size_t)mchunk * 2 + msub) * BATCH + b) * NQ + ntile * TQ + nsub * 16 + l15] = v;
        }
    }

    // ---- U partials: plain coalesced stores, layout [ms][b][n][c] ----
    float* ubase = Up + (((size_t)mchunk * BATCH + b) * NQ + ntile * TQ) * CVD
                 + (size_t)(npair * 32) * CVD + chalf * 128;
    #pragma unroll
    for (int nsi2 = 0; nsi2 < 2; ++nsi2) {
        #pragma unroll
        for (int cs = 0; cs < 8; ++cs) {
            #pragma unroll
            for (int r = 0; r < 4; ++r) {
                int n_local = nsi2 * 16 + quad * 4 + r;
                ubase[(size_t)n_local * CVD + cs * 16 + l15] = O[nsi2][cs][r];
            }
        }
    }
}

// ---------------------------------------------------------------------------
// reduce_div: out[b,256+c,n] = (sum_ms Up[ms][b][n][c]) / (sum_s Lp[s][b][n])
// Grid: 256 = b(2) x nslab(128, 16 n each). Block 256.
// ---------------------------------------------------------------------------
__global__ __launch_bounds__(256) void reduce_div(const float* __restrict__ Up,
                                                  const float* __restrict__ Lp,
                                                  float* __restrict__ out) {
    __shared__ float lds[16 * 257];
    const int tid = threadIdx.x;
    const int b   = blockIdx.x >> 7;
    const int n0  = (blockIdx.x & 127) * 16;

    float acc[16];
    #pragma unroll
    for (int j = 0; j < 16; ++j) acc[j] = 0.f;

    for (int ms = 0; ms < MSPLIT; ++ms) {
        const float* sb = Up + (((size_t)ms * BATCH + b) * NQ + n0) * CVD + tid * 16;
        #pragma unroll
        for (int k = 0; k < 4; ++k) {
            float4 v = *(const float4*)(sb + k * 4);
            acc[k * 4 + 0] += v.x; acc[k * 4 + 1] += v.y;
            acc[k * 4 + 2] += v.z; acc[k * 4 + 3] += v.w;
        }
    }

    const int n_local = tid >> 4;
    const int c0      = (tid & 15) * 16;
    float Lsum = 0.f;
    #pragma unroll
    for (int s = 0; s < MSPLIT * 2; ++s)
        Lsum += Lp[((size_t)s * BATCH + b) * NQ + n0 + n_local];
    const float inv = 1.0f / Lsum;

    #pragma unroll
    for (int j = 0; j < 16; ++j)
        lds[n_local * 257 + c0 + j] = acc[j] * inv;
    __syncthreads();

    // write out[b][256+c][n0..n0+16): c = tid
    float* ob = out + ((size_t)(b * 512 + 256 + tid)) * NQ + n0;
    #pragma unroll
    for (int k = 0; k < 4; ++k) {
        float4 v;
        v.x = lds[(4 * k + 0) * 257 + tid];
        v.y = lds[(4 * k + 1) * 257 + tid];
        v.z = lds[(4 * k + 2) * 257 + tid];
        v.w = lds[(4 * k + 3) * 257 + tid];
        *(float4*)(ob + 4 * k) = v;
    }
}

extern "C" void kernel_launch(void* const* d_in, const int* in_sizes, int n_in,
                              void* d_out, int out_size, void* d_ws, size_t ws_size,
                              hipStream_t stream) {
    const float* qv = (const float*)d_in[0];   // query_value       [2,256,64,128]
    const float* mk = (const float*)d_in[1];   // memory_keys_low   [2,4,64,32,64]
    const float* mv = (const float*)d_in[2];   // memory_values_low [2,4,256,32,64]
    const float* qk = (const float*)d_in[3];   // query_key_low     [2,64,32,64]
    float* out = (float*)d_out;                // [2,512,32,64] fp32

    u16*   vb  = (u16*)((char*)d_ws + WS_VB);
    u16*   khi = (u16*)((char*)d_ws + WS_KHI);
    u16*   klo = (u16*)((char*)d_ws + WS_KLO);
    u16*   qhi = (u16*)((char*)d_ws + WS_QHI);
    u16*   qlo = (u16*)((char*)d_ws + WS_QLO);
    float* Lp  = (float*)((char*)d_ws + WS_LP);
    float* Up  = (float*)((char*)d_ws + WS_UP);

    prep_fused<<<6784, 256, 0, stream>>>(qv, mk, qk, mv, out, vb, khi, klo, qhi, qlo);
    flash_attn<<<512, 256, 0, stream>>>(khi, klo, vb, qhi, qlo, Up, Lp);
    reduce_div<<<256, 256, 0, stream>>>(Up, Lp, out);
}